// Round 4
// baseline (26511.469 us; speedup 1.0000x reference)
//
#include <hip/hip_runtime.h>
#include <hip/hip_bf16.h>

#define T_STEPS 256
#define BATCH   128
#define IDIM    512
#define HDIM    1024
#define NLAYERS 4
#define G3      (3 * HDIM)
#define BH      (BATCH * HDIM)   // 131072 elements

typedef __bf16 bf16_t;
typedef __bf16 bf16x4 __attribute__((ext_vector_type(4)));
typedef __bf16 bf16x8 __attribute__((ext_vector_type(8)));
typedef float  f32x4  __attribute__((ext_vector_type(4)));
typedef unsigned long long ull_t;

__device__ __forceinline__ float sigm_f(float x) { return 1.0f / (1.0f + __expf(-x)); }
__device__ __forceinline__ float tanh_f(float x) { return 1.0f - 2.0f / (__expf(2.0f * x) + 1.0f); }

// fp32 -> bf16, 4 elements per thread. n4 = n/4.
__global__ void cvt_f2b(const float* __restrict__ s, bf16_t* __restrict__ d, int n4) {
    int i = blockIdx.x * blockDim.x + threadIdx.x;
    if (i < n4) {
        f32x4 v = ((const f32x4*)s)[i];
        bf16x4 o;
        o[0] = (bf16_t)v[0]; o[1] = (bf16_t)v[1];
        o[2] = (bf16_t)v[2]; o[3] = (bf16_t)v[3];
        ((bf16x4*)d)[i] = o;
    }
}

// fp32 h -> bf16 hi/lo split, 4 per thread over BH elements.
__global__ void split_h(const float* __restrict__ s,
                        bf16_t* __restrict__ hi, bf16_t* __restrict__ lo) {
    int i = blockIdx.x * blockDim.x + threadIdx.x;  // < BH/4
    f32x4 v = ((const f32x4*)s)[i];
    bf16x4 h, l;
#pragma unroll
    for (int j = 0; j < 4; ++j) {
        bf16_t t = (bf16_t)v[j];
        h[j] = t;
        l[j] = (bf16_t)(v[j] - (float)t);
    }
    ((bf16x4*)hi)[i] = h;
    ((bf16x4*)lo)[i] = l;
}

// 8-byte copy, n ULLs with n/256 blocks of 256.
__global__ void copy_kernel(const ull_t* __restrict__ src, ull_t* __restrict__ dst) {
    int i = blockIdx.x * blockDim.x + threadIdx.x;
    dst[i] = src[i];
}

// One GRU timestep. Grid (64 col-blocks, 8 batch-blocks) x 64 threads (1 wave).
// Wave computes a 16(batch) x 16(hidden) tile via MFMA 16x16x32 bf16.
// Inputs x_t are fp32 (converted to bf16 in-register); weights pre-converted
// bf16 in ws; h carried as bf16 hi+lo split (~fp32 accuracy) in ws.
// Tail optionally copies ys[t+1] (fp32) into the stash ping-pong so layers >0
// can run in-place on the ys region of d_out.
template <int HIN>
__global__ __launch_bounds__(64)
void gru_step(const float*  __restrict__ x_t,      // (B, HIN) fp32 input slice
              const bf16_t* __restrict__ w_ih,     // (3H, HIN) bf16
              const bf16_t* __restrict__ w_hh,     // (3H, H) bf16
              const float*  __restrict__ b_ih,     // (3H) fp32
              const float*  __restrict__ b_hh,     // (3H) fp32
              const bf16_t* __restrict__ h_in_hi,  // (B, H)
              const bf16_t* __restrict__ h_in_lo,  // (B, H)
              bf16_t* __restrict__ h_out_hi,
              bf16_t* __restrict__ h_out_lo,
              float*  __restrict__ y_t,            // (B, H) fp32 output slice
              const int* __restrict__ lengths,     // (B)
              int t,
              float* __restrict__ h_final,         // (B, H) fp32 or nullptr
              const ull_t* __restrict__ cp_src,    // stash copy src, or nullptr
              ull_t* __restrict__ cp_dst)
{
    const int lane = threadIdx.x;
    const int cq   = lane & 15;
    const int quad = lane >> 4;
    const int c0   = blockIdx.x * 16;  // hidden-column tile base
    const int m0   = blockIdx.y * 16;  // batch tile base

    // A fragments: A[m = lane&15][k = quad*8 + j]
    const float*  aXp  = x_t     + (size_t)(m0 + cq) * HIN  + quad * 8;
    const bf16_t* aHhi = h_in_hi + (size_t)(m0 + cq) * HDIM + quad * 8;
    const bf16_t* aHlo = h_in_lo + (size_t)(m0 + cq) * HDIM + quad * 8;
    // B fragments (weights stored N x K row-major): row n = c0+cq, k = quad*8+j
    const bf16_t* bI0 = w_ih + (size_t)(0 * HDIM + c0 + cq) * HIN + quad * 8;
    const bf16_t* bI1 = w_ih + (size_t)(1 * HDIM + c0 + cq) * HIN + quad * 8;
    const bf16_t* bI2 = w_ih + (size_t)(2 * HDIM + c0 + cq) * HIN + quad * 8;
    const bf16_t* bH0 = w_hh + (size_t)(0 * HDIM + c0 + cq) * HDIM + quad * 8;
    const bf16_t* bH1 = w_hh + (size_t)(1 * HDIM + c0 + cq) * HDIM + quad * 8;
    const bf16_t* bH2 = w_hh + (size_t)(2 * HDIM + c0 + cq) * HDIM + quad * 8;

    f32x4 accI0 = {0.f, 0.f, 0.f, 0.f}, accI1 = accI0, accI2 = accI0;
    f32x4 accH0 = accI0, accH1 = accI0, accH2 = accI0;

    // Input-part GEMM: gi = x_t @ W_ih^T (x converted fp32->bf16 in-register)
#pragma unroll 4
    for (int k = 0; k < HIN; k += 32) {
        f32x4 a0 = *(const f32x4*)(aXp + k);
        f32x4 a1 = *(const f32x4*)(aXp + k + 4);
        bf16x8 a;
        a[0] = (bf16_t)a0[0]; a[1] = (bf16_t)a0[1];
        a[2] = (bf16_t)a0[2]; a[3] = (bf16_t)a0[3];
        a[4] = (bf16_t)a1[0]; a[5] = (bf16_t)a1[1];
        a[6] = (bf16_t)a1[2]; a[7] = (bf16_t)a1[3];
        accI0 = __builtin_amdgcn_mfma_f32_16x16x32_bf16(a, *(const bf16x8*)(bI0 + k), accI0, 0, 0, 0);
        accI1 = __builtin_amdgcn_mfma_f32_16x16x32_bf16(a, *(const bf16x8*)(bI1 + k), accI1, 0, 0, 0);
        accI2 = __builtin_amdgcn_mfma_f32_16x16x32_bf16(a, *(const bf16x8*)(bI2 + k), accI2, 0, 0, 0);
    }
    // Hidden-part GEMM: gh = h @ W_hh^T, h = hi + lo (split precision)
#pragma unroll 2
    for (int k = 0; k < HDIM; k += 32) {
        bf16x8 b0  = *(const bf16x8*)(bH0 + k);
        bf16x8 b1  = *(const bf16x8*)(bH1 + k);
        bf16x8 b2  = *(const bf16x8*)(bH2 + k);
        bf16x8 ahi = *(const bf16x8*)(aHhi + k);
        bf16x8 alo = *(const bf16x8*)(aHlo + k);
        accH0 = __builtin_amdgcn_mfma_f32_16x16x32_bf16(ahi, b0, accH0, 0, 0, 0);
        accH1 = __builtin_amdgcn_mfma_f32_16x16x32_bf16(ahi, b1, accH1, 0, 0, 0);
        accH2 = __builtin_amdgcn_mfma_f32_16x16x32_bf16(ahi, b2, accH2, 0, 0, 0);
        accH0 = __builtin_amdgcn_mfma_f32_16x16x32_bf16(alo, b0, accH0, 0, 0, 0);
        accH1 = __builtin_amdgcn_mfma_f32_16x16x32_bf16(alo, b1, accH1, 0, 0, 0);
        accH2 = __builtin_amdgcn_mfma_f32_16x16x32_bf16(alo, b2, accH2, 0, 0, 0);
    }

    // Gate math. C/D layout: col(n) = lane&15, row(m) = quad*4 + reg.
    const int col = c0 + cq;
    const float vbir = b_ih[col];
    const float vbiz = b_ih[HDIM + col];
    const float vbin = b_ih[2 * HDIM + col];
    const float vbhr = b_hh[col];
    const float vbhz = b_hh[HDIM + col];
    const float vbhn = b_hh[2 * HDIM + col];

#pragma unroll
    for (int i = 0; i < 4; ++i) {
        const int row = m0 + quad * 4 + i;           // batch index
        const size_t oh = (size_t)row * HDIM + col;
        const float hold = (float)h_in_hi[oh] + (float)h_in_lo[oh];
        const float r = sigm_f(accI0[i] + accH0[i] + vbir + vbhr);
        const float z = sigm_f(accI1[i] + accH1[i] + vbiz + vbhz);
        const float n = tanh_f(accI2[i] + vbin + r * (accH2[i] + vbhn));
        const float hnew = (1.0f - z) * n + z * hold;
        const bool msk = t < lengths[row];
        const float hnext = msk ? hnew : hold;
        const bf16_t hi = (bf16_t)hnext;
        h_out_hi[oh] = hi;
        h_out_lo[oh] = (bf16_t)(hnext - (float)hi);
        y_t[oh] = msk ? hnew : 0.0f;
        if (h_final) h_final[oh] = hnext;
    }

    // Stash ys[t+1] (fp32, 65536 ULLs over 32768 lanes -> 2 each).
    if (cp_src) {
        const int tid = ((blockIdx.y * 64 + blockIdx.x) * 64) + lane;  // 0..32767
        cp_dst[tid]         = cp_src[tid];
        cp_dst[tid + 32768] = cp_src[tid + 32768];
    }
}

extern "C" void kernel_launch(void* const* d_in, const int* in_sizes, int n_in,
                              void* d_out, int out_size, void* d_ws, size_t ws_size,
                              hipStream_t stream) {
    const float* x         = (const float*)d_in[0];
    const float* hidden    = (const float*)d_in[1];
    const float* w_ih0     = (const float*)d_in[2];
    const float* w_ih_rest = (const float*)d_in[3];
    const float* w_hh      = (const float*)d_in[4];
    const float* b_ih      = (const float*)d_in[5];
    const float* b_hh      = (const float*)d_in[6];
    const int*   lengths   = (const int*)d_in[8];

    float* ys   = (float*)d_out;               // (T, B, H) fp32
    float* hfin = ys + (size_t)T_STEPS * BH;   // (L, B, H) fp32

    // Workspace layout (~49 MB): bf16 weights, h hi/lo carry, fp32 stash.
    char* ws = (char*)d_ws;
    bf16_t* wb_ih0  = (bf16_t*)ws;                                   // 3072*512
    bf16_t* wb_rest = wb_ih0 + (size_t)G3 * IDIM;                    // 3*3072*1024
    bf16_t* wb_hh   = wb_rest + (size_t)(NLAYERS - 1) * G3 * HDIM;   // 4*3072*1024
    bf16_t* hhi0 = wb_hh + (size_t)NLAYERS * G3 * HDIM;
    bf16_t* hlo0 = hhi0 + BH;
    bf16_t* hhi1 = hlo0 + BH;
    bf16_t* hlo1 = hhi1 + BH;
    float*  stash0 = (float*)(hlo1 + BH);      // (B,H) fp32 ping
    float*  stash1 = stash0 + BH;              // (B,H) fp32 pong

    // Convert all weights fp32 -> bf16 once.
    {
        int n4;
        n4 = G3 * IDIM / 4;
        cvt_f2b<<<(n4 + 255) / 256, 256, 0, stream>>>(w_ih0, wb_ih0, n4);
        n4 = (NLAYERS - 1) * G3 * HDIM / 4;
        cvt_f2b<<<(n4 + 255) / 256, 256, 0, stream>>>(w_ih_rest, wb_rest, n4);
        n4 = NLAYERS * G3 * HDIM / 4;
        cvt_f2b<<<(n4 + 255) / 256, 256, 0, stream>>>(w_hh, wb_hh, n4);
    }

    dim3 grid(HDIM / 16, BATCH / 16);  // (64, 8)
    dim3 block(64);

    for (int l = 0; l < NLAYERS; ++l) {
        const bf16_t* wb_ih_l = (l == 0) ? wb_ih0 : (wb_rest + (size_t)(l - 1) * G3 * HDIM);
        const bf16_t* wb_hh_l = wb_hh + (size_t)l * G3 * HDIM;
        const float*  b_ih_l  = b_ih + (size_t)l * G3;
        const float*  b_hh_l  = b_hh + (size_t)l * G3;

        // Seed carry slot 0 with this layer's initial hidden state.
        split_h<<<BH / 4 / 256, 256, 0, stream>>>(hidden + (size_t)l * BH, hhi0, hlo0);

        if (l > 0) {
            // Seed the stash with ys[0] (previous layer's t=0 output).
            copy_kernel<<<BH * 4 / 8 / 256, 256, 0, stream>>>(
                (const ull_t*)ys, (ull_t*)stash0);
        }

        for (int t = 0; t < T_STEPS; ++t) {
            // step t reads slot (t&1), writes slot ((t+1)&1)
            const bool rd0 = ((t & 1) == 0);
            const bf16_t* hi_hi = rd0 ? hhi0 : hhi1;
            const bf16_t* hi_lo = rd0 ? hlo0 : hlo1;
            bf16_t* ho_hi = rd0 ? hhi1 : hhi0;
            bf16_t* ho_lo = rd0 ? hlo1 : hlo0;
            float* hfinal = (t == T_STEPS - 1) ? (hfin + (size_t)l * BH) : nullptr;
            float* y_t = ys + (size_t)t * BH;

            if (l == 0) {
                const float* x_t = x + (size_t)t * BATCH * IDIM;
                gru_step<IDIM><<<grid, block, 0, stream>>>(
                    x_t, wb_ih_l, wb_hh_l, b_ih_l, b_hh_l, hi_hi, hi_lo,
                    ho_hi, ho_lo, y_t, lengths, t, hfinal, nullptr, nullptr);
            } else {
                const float* x_t = rd0 ? stash0 : stash1;
                const ull_t* cp_src = nullptr;
                ull_t* cp_dst = nullptr;
                if (t + 1 < T_STEPS) {
                    cp_src = (const ull_t*)(ys + (size_t)(t + 1) * BH);
                    cp_dst = (ull_t*)(rd0 ? stash1 : stash0);
                }
                gru_step<HDIM><<<grid, block, 0, stream>>>(
                    x_t, wb_ih_l, wb_hh_l, b_ih_l, b_hh_l, hi_hi, hi_lo,
                    ho_hi, ho_lo, y_t, lengths, t, hfinal, cp_src, cp_dst);
            }
        }
    }
}

// Round 5
// 19458.571 us; speedup vs baseline: 1.3625x; 1.3625x over previous
//
#include <hip/hip_runtime.h>
#include <hip/hip_bf16.h>

#define T_STEPS 256
#define BATCH   128
#define IDIM    512
#define HDIM    1024
#define NLAYERS 4
#define G3      (3 * HDIM)
#define BH      (BATCH * HDIM)   // 131072 elements
#define CHUNK   16               // timesteps per gi precompute chunk
#define CROWS   (CHUNK * BATCH)  // 2048 rows per chunk GEMM

typedef __bf16 bf16_t;
typedef __bf16 bf16x4 __attribute__((ext_vector_type(4)));
typedef __bf16 bf16x8 __attribute__((ext_vector_type(8)));
typedef float  f32x4  __attribute__((ext_vector_type(4)));

__device__ __forceinline__ float sigm_f(float x) { return 1.0f / (1.0f + __expf(-x)); }
__device__ __forceinline__ float tanh_f(float x) { return 1.0f - 2.0f / (__expf(2.0f * x) + 1.0f); }

__device__ __forceinline__ bf16x8 cvt8(const float* p) {
    f32x4 v0 = *(const f32x4*)p;
    f32x4 v1 = *(const f32x4*)(p + 4);
    bf16x8 o;
    o[0] = (bf16_t)v0[0]; o[1] = (bf16_t)v0[1]; o[2] = (bf16_t)v0[2]; o[3] = (bf16_t)v0[3];
    o[4] = (bf16_t)v1[0]; o[5] = (bf16_t)v1[1]; o[6] = (bf16_t)v1[2]; o[7] = (bf16_t)v1[3];
    return o;
}

// fp32 -> bf16, 4 elements per thread. n4 = n/4.
__global__ void cvt_f2b(const float* __restrict__ s, bf16_t* __restrict__ d, int n4) {
    int i = blockIdx.x * blockDim.x + threadIdx.x;
    if (i < n4) {
        f32x4 v = ((const f32x4*)s)[i];
        bf16x4 o;
        o[0] = (bf16_t)v[0]; o[1] = (bf16_t)v[1];
        o[2] = (bf16_t)v[2]; o[3] = (bf16_t)v[3];
        ((bf16x4*)d)[i] = o;
    }
}

// fp32 h -> bf16 hi/lo split, 4 per thread over BH elements.
__global__ void split_h(const float* __restrict__ s,
                        bf16_t* __restrict__ hi, bf16_t* __restrict__ lo) {
    int i = blockIdx.x * blockDim.x + threadIdx.x;  // < BH/4
    f32x4 v = ((const f32x4*)s)[i];
    bf16x4 h, l;
#pragma unroll
    for (int j = 0; j < 4; ++j) {
        bf16_t t = (bf16_t)v[j];
        h[j] = t;
        l[j] = (bf16_t)(v[j] - (float)t);
    }
    ((bf16x4*)hi)[i] = h;
    ((bf16x4*)lo)[i] = l;
}

// Phase A: gi[chunk] = ys_rows @ W_ih^T + b_ih.  fp32 in (converted in-register),
// bf16 weights, fp32 out. One wave per WG; wave computes a 32x64 C-tile
// (2 m-frags x 4 n-frags). Grid (48 n-groups, 64 m-groups) x 64 threads.
template <int HIN>
__global__ __launch_bounds__(64)
void gi_gemm(const float*  __restrict__ ysrc,   // layer input, row-major (.., HIN)
             const bf16_t* __restrict__ w_ih,   // (3H, HIN) bf16
             const float*  __restrict__ b_ih,   // (3H) fp32
             float* __restrict__ gi,            // (CROWS, 3072) fp32 out
             int row0)                          // global row offset = t0*BATCH
{
    const int lane = threadIdx.x;
    const int cq   = lane & 15;
    const int quad = lane >> 4;
    const int n0   = blockIdx.x * 64;  // col group
    const int m0   = blockIdx.y * 32;  // row group (within chunk)

    const float* a0p = ysrc + (size_t)(row0 + m0 + cq) * HIN + quad * 8;
    const float* a1p = a0p + (size_t)16 * HIN;
    const bf16_t* b0p = w_ih + (size_t)(n0 + cq) * HIN + quad * 8;
    const bf16_t* b1p = b0p + (size_t)16 * HIN;
    const bf16_t* b2p = b0p + (size_t)32 * HIN;
    const bf16_t* b3p = b0p + (size_t)48 * HIN;

    f32x4 a00{0,0,0,0}, a01 = a00, a02 = a00, a03 = a00;
    f32x4 a10 = a00, a11 = a00, a12 = a00, a13 = a00;

#pragma unroll 4
    for (int k = 0; k < HIN; k += 32) {
        bf16x8 fa0 = cvt8(a0p + k);
        bf16x8 fa1 = cvt8(a1p + k);
        bf16x8 fb0 = *(const bf16x8*)(b0p + k);
        bf16x8 fb1 = *(const bf16x8*)(b1p + k);
        bf16x8 fb2 = *(const bf16x8*)(b2p + k);
        bf16x8 fb3 = *(const bf16x8*)(b3p + k);
        a00 = __builtin_amdgcn_mfma_f32_16x16x32_bf16(fa0, fb0, a00, 0, 0, 0);
        a01 = __builtin_amdgcn_mfma_f32_16x16x32_bf16(fa0, fb1, a01, 0, 0, 0);
        a02 = __builtin_amdgcn_mfma_f32_16x16x32_bf16(fa0, fb2, a02, 0, 0, 0);
        a03 = __builtin_amdgcn_mfma_f32_16x16x32_bf16(fa0, fb3, a03, 0, 0, 0);
        a10 = __builtin_amdgcn_mfma_f32_16x16x32_bf16(fa1, fb0, a10, 0, 0, 0);
        a11 = __builtin_amdgcn_mfma_f32_16x16x32_bf16(fa1, fb1, a11, 0, 0, 0);
        a12 = __builtin_amdgcn_mfma_f32_16x16x32_bf16(fa1, fb2, a12, 0, 0, 0);
        a13 = __builtin_amdgcn_mfma_f32_16x16x32_bf16(fa1, fb3, a13, 0, 0, 0);
    }

    // Fold b_ih into gi. C/D layout: col = lane&15, row = quad*4 + reg.
    const float bb0 = b_ih[n0 + 0  + cq];
    const float bb1 = b_ih[n0 + 16 + cq];
    const float bb2 = b_ih[n0 + 32 + cq];
    const float bb3 = b_ih[n0 + 48 + cq];

#pragma unroll
    for (int i = 0; i < 4; ++i) {
        const int r0 = m0 + quad * 4 + i;
        const int r1 = r0 + 16;
        float* g0 = gi + (size_t)r0 * G3 + n0 + cq;
        float* g1 = gi + (size_t)r1 * G3 + n0 + cq;
        g0[0]  = a00[i] + bb0;  g0[16] = a01[i] + bb1;
        g0[32] = a02[i] + bb2;  g0[48] = a03[i] + bb3;
        g1[0]  = a10[i] + bb0;  g1[16] = a11[i] + bb1;
        g1[32] = a12[i] + bb2;  g1[48] = a13[i] + bb3;
    }
}

// Phase B: one GRU timestep, hidden GEMM only (gi precomputed).
// Grid (64 col-tiles, 8 batch-tiles) x 256 threads (4 waves = K-quarters).
// Each wave computes 3 gate accumulators for its 16x16 tile over K=256
// (hi+lo split of h). LDS reduction across the 4 K-quarters, then wave 0
// does the gate math + state/output writes.
__global__ __launch_bounds__(256)
void gru_step2(const float*  __restrict__ gi_t,   // (B, 3H) fp32, this timestep
               const bf16_t* __restrict__ w_hh,   // (3H, H) bf16
               const float*  __restrict__ b_hh,   // (3H) fp32
               const bf16_t* __restrict__ h_in_hi,
               const bf16_t* __restrict__ h_in_lo,
               bf16_t* __restrict__ h_out_hi,
               bf16_t* __restrict__ h_out_lo,
               float*  __restrict__ y_t,          // (B, H) fp32 output slice
               const int* __restrict__ lengths,
               int t,
               float* __restrict__ h_final)       // (B, H) fp32 or nullptr
{
    __shared__ f32x4 red[4][3][64];   // [k-quarter][gate][lane]

    const int tid  = threadIdx.x;
    const int s    = tid >> 6;        // K-quarter 0..3
    const int lane = tid & 63;
    const int cq   = lane & 15;
    const int quad = lane >> 4;
    const int c0   = blockIdx.x * 16; // hidden col tile
    const int m0   = blockIdx.y * 16; // batch tile

    const bf16_t* ap_hi = h_in_hi + (size_t)(m0 + cq) * HDIM + s * 256 + quad * 8;
    const bf16_t* ap_lo = h_in_lo + (size_t)(m0 + cq) * HDIM + s * 256 + quad * 8;
    const bf16_t* bp0 = w_hh + (size_t)(0 * HDIM + c0 + cq) * HDIM + s * 256 + quad * 8;
    const bf16_t* bp1 = w_hh + (size_t)(1 * HDIM + c0 + cq) * HDIM + s * 256 + quad * 8;
    const bf16_t* bp2 = w_hh + (size_t)(2 * HDIM + c0 + cq) * HDIM + s * 256 + quad * 8;

    f32x4 ac0{0,0,0,0}, ac1 = ac0, ac2 = ac0;

#pragma unroll
    for (int k = 0; k < 256; k += 32) {
        bf16x8 ahi = *(const bf16x8*)(ap_hi + k);
        bf16x8 alo = *(const bf16x8*)(ap_lo + k);
        bf16x8 b0  = *(const bf16x8*)(bp0 + k);
        bf16x8 b1  = *(const bf16x8*)(bp1 + k);
        bf16x8 b2  = *(const bf16x8*)(bp2 + k);
        ac0 = __builtin_amdgcn_mfma_f32_16x16x32_bf16(ahi, b0, ac0, 0, 0, 0);
        ac1 = __builtin_amdgcn_mfma_f32_16x16x32_bf16(ahi, b1, ac1, 0, 0, 0);
        ac2 = __builtin_amdgcn_mfma_f32_16x16x32_bf16(ahi, b2, ac2, 0, 0, 0);
        ac0 = __builtin_amdgcn_mfma_f32_16x16x32_bf16(alo, b0, ac0, 0, 0, 0);
        ac1 = __builtin_amdgcn_mfma_f32_16x16x32_bf16(alo, b1, ac1, 0, 0, 0);
        ac2 = __builtin_amdgcn_mfma_f32_16x16x32_bf16(alo, b2, ac2, 0, 0, 0);
    }
    red[s][0][lane] = ac0;
    red[s][1][lane] = ac1;
    red[s][2][lane] = ac2;
    __syncthreads();

    if (s == 0) {
        const int col = c0 + cq;
        const float bhr = b_hh[col];
        const float bhz = b_hh[HDIM + col];
        const float bhn = b_hh[2 * HDIM + col];
#pragma unroll
        for (int i = 0; i < 4; ++i) {
            const int row = m0 + quad * 4 + i;   // batch index
            const size_t oh = (size_t)row * HDIM + col;
            const float hr = red[0][0][lane][i] + red[1][0][lane][i]
                           + red[2][0][lane][i] + red[3][0][lane][i];
            const float hz = red[0][1][lane][i] + red[1][1][lane][i]
                           + red[2][1][lane][i] + red[3][1][lane][i];
            const float hn = red[0][2][lane][i] + red[1][2][lane][i]
                           + red[2][2][lane][i] + red[3][2][lane][i];
            const float* gr = gi_t + (size_t)row * G3;
            const float ir  = gr[col];               // includes b_ih
            const float iz  = gr[HDIM + col];
            const float inn = gr[2 * HDIM + col];
            const float hold = (float)h_in_hi[oh] + (float)h_in_lo[oh];
            const float r = sigm_f(ir + hr + bhr);
            const float z = sigm_f(iz + hz + bhz);
            const float n = tanh_f(inn + r * (hn + bhn));
            const float hnew = (1.0f - z) * n + z * hold;
            const bool msk = t < lengths[row];
            const float hnext = msk ? hnew : hold;
            const bf16_t hi = (bf16_t)hnext;
            h_out_hi[oh] = hi;
            h_out_lo[oh] = (bf16_t)(hnext - (float)hi);
            y_t[oh] = msk ? hnew : 0.0f;
            if (h_final) h_final[oh] = hnext;
        }
    }
}

extern "C" void kernel_launch(void* const* d_in, const int* in_sizes, int n_in,
                              void* d_out, int out_size, void* d_ws, size_t ws_size,
                              hipStream_t stream) {
    const float* x         = (const float*)d_in[0];
    const float* hidden    = (const float*)d_in[1];
    const float* w_ih0     = (const float*)d_in[2];
    const float* w_ih_rest = (const float*)d_in[3];
    const float* w_hh      = (const float*)d_in[4];
    const float* b_ih      = (const float*)d_in[5];
    const float* b_hh      = (const float*)d_in[6];
    const int*   lengths   = (const int*)d_in[8];

    float* ys   = (float*)d_out;               // (T, B, H) fp32
    float* hfin = ys + (size_t)T_STEPS * BH;   // (L, B, H) fp32

    // Workspace (~74 MB): bf16 weights (47.2), h hi/lo carry (1), gi chunk (25.2).
    char* ws = (char*)d_ws;
    bf16_t* wb_ih0  = (bf16_t*)ws;                                   // 3072*512
    bf16_t* wb_rest = wb_ih0 + (size_t)G3 * IDIM;                    // 3*3072*1024
    bf16_t* wb_hh   = wb_rest + (size_t)(NLAYERS - 1) * G3 * HDIM;   // 4*3072*1024
    bf16_t* hhi0 = wb_hh + (size_t)NLAYERS * G3 * HDIM;
    bf16_t* hlo0 = hhi0 + BH;
    bf16_t* hhi1 = hlo0 + BH;
    bf16_t* hlo1 = hhi1 + BH;
    float*  gi   = (float*)(hlo1 + BH);        // (CROWS, 3H) fp32 chunk buffer

    // Convert all weights fp32 -> bf16 once.
    {
        int n4;
        n4 = G3 * IDIM / 4;
        cvt_f2b<<<(n4 + 255) / 256, 256, 0, stream>>>(w_ih0, wb_ih0, n4);
        n4 = (NLAYERS - 1) * G3 * HDIM / 4;
        cvt_f2b<<<(n4 + 255) / 256, 256, 0, stream>>>(w_ih_rest, wb_rest, n4);
        n4 = NLAYERS * G3 * HDIM / 4;
        cvt_f2b<<<(n4 + 255) / 256, 256, 0, stream>>>(w_hh, wb_hh, n4);
    }

    dim3 gridA(G3 / 64, CROWS / 32);   // (48, 64)
    dim3 gridB(HDIM / 16, BATCH / 16); // (64, 8)

    for (int l = 0; l < NLAYERS; ++l) {
        const bf16_t* wb_ih_l = (l == 0) ? wb_ih0 : (wb_rest + (size_t)(l - 1) * G3 * HDIM);
        const bf16_t* wb_hh_l = wb_hh + (size_t)l * G3 * HDIM;
        const float*  b_ih_l  = b_ih + (size_t)l * G3;
        const float*  b_hh_l  = b_hh + (size_t)l * G3;

        // Seed carry slot 0 with this layer's initial hidden state.
        split_h<<<BH / 4 / 256, 256, 0, stream>>>(hidden + (size_t)l * BH, hhi0, hlo0);

        for (int c = 0; c < T_STEPS / CHUNK; ++c) {
            const int t0 = c * CHUNK;
            // Phase A: gi for this chunk (reads layer input BEFORE the in-place
            // step kernels below overwrite these ys slices).
            if (l == 0) {
                gi_gemm<IDIM><<<gridA, 64, 0, stream>>>(x, wb_ih_l, b_ih_l, gi, t0 * BATCH);
            } else {
                gi_gemm<HDIM><<<gridA, 64, 0, stream>>>(ys, wb_ih_l, b_ih_l, gi, t0 * BATCH);
            }
            // Phase B: sequential steps within the chunk.
            for (int tt = 0; tt < CHUNK; ++tt) {
                const int t = t0 + tt;
                const bool rd0 = ((t & 1) == 0);
                const bf16_t* hi_hi = rd0 ? hhi0 : hhi1;
                const bf16_t* hi_lo = rd0 ? hlo0 : hlo1;
                bf16_t* ho_hi = rd0 ? hhi1 : hhi0;
                bf16_t* ho_lo = rd0 ? hlo1 : hlo0;
                float* hfinal = (t == T_STEPS - 1) ? (hfin + (size_t)l * BH) : nullptr;
                gru_step2<<<gridB, 256, 0, stream>>>(
                    gi + (size_t)tt * BATCH * G3, wb_hh_l, b_hh_l,
                    hi_hi, hi_lo, ho_hi, ho_lo,
                    ys + (size_t)t * BH, lengths, t, hfinal);
            }
        }
    }
}